// Round 2
// baseline (1973.414 us; speedup 1.0000x reference)
//
#include <hip/hip_runtime.h>

#define GLOBAL_AS __attribute__((address_space(1)))
#define LDS_AS    __attribute__((address_space(3)))

typedef __bf16 bf16x8 __attribute__((ext_vector_type(8)));
typedef float  floatx4 __attribute__((ext_vector_type(4)));
typedef unsigned short ushort8 __attribute__((ext_vector_type(8)));

static constexpr int M_BATCH = 4096;
static constexpr int NPTS    = 512;
static constexpr int EMB     = 2048;
static constexpr int F0      = 1023;     // 2*NPTS-1
static constexpr int F0P     = 1024;     // padded feature count, K multiple of 64
static constexpr int K0      = 9 * F0P;  // 9216
static constexpr int K12     = 9 * EMB;  // 18432

// ---- float -> bf16 round-to-nearest-even ----
__device__ __forceinline__ unsigned short f2bf(float f) {
    unsigned int u = __float_as_uint(f);
    u += 0x7fffu + ((u >> 16) & 1u);
    return (unsigned short)(u >> 16);
}

// ---- relu + 8 cubic B-spline bases, exactly mirroring the reference recursion ----
// grid values are compile-time constants -> divisions fold to constant multiplies.
__device__ __forceinline__ void kan_phi(float x, float* v) {
    float g[12];
    #pragma unroll
    for (int i = 0; i < 12; ++i) g[i] = (float)(i - 3) * 0.4f - 1.0f;
    float b[11];
    #pragma unroll
    for (int i = 0; i < 11; ++i) b[i] = (x >= g[i] && x < g[i + 1]) ? 1.0f : 0.0f;
    #pragma unroll
    for (int k = 1; k <= 3; ++k) {
        #pragma unroll
        for (int i = 0; i + k < 11; ++i) {
            float left  = (x - g[i]) / (g[i + k] - g[i]);
            float right = (g[i + k + 1] - x) / (g[i + k + 1] - g[i + 1]);
            b[i] = left * b[i] + right * b[i + 1];
        }
    }
    v[0] = x > 0.0f ? x : 0.0f;
    #pragma unroll
    for (int i = 0; i < 8; ++i) v[1 + i] = b[i];
}

// ---- build h0 (4096 x 1023): interleave xs[:, :-1], ys[:, :-1], then xs[:, -1] ----
__global__ void build_h0_kernel(const float* __restrict__ xs,
                                const float* __restrict__ ys,
                                float* __restrict__ h0) {
    int idx = blockIdx.x * blockDim.x + threadIdx.x;
    if (idx >= M_BATCH * F0) return;
    int n = idx / F0, c = idx - n * F0;
    float v;
    if (c == F0 - 1) v = xs[n * NPTS + NPTS - 1];
    else {
        int i = c >> 1;
        v = (c & 1) ? ys[n * NPTS + i] : xs[n * NPTS + i];
    }
    h0[idx] = v;
}

// ---- expand h (N x F fp32) -> Phi (N x 9*Fp bf16), BASIS-MAJOR K layout:
//      Phi[n, j*Fp + f].  Thread handles 8 adjacent features -> 9 coalesced
//      16B ushort8 stores. ----
__global__ void expand_kernel(const float* __restrict__ h,
                              unsigned short* __restrict__ phi,
                              int Nrows, int F, int Fp) {
    int ng = Fp >> 3;
    int idx = blockIdx.x * blockDim.x + threadIdx.x;
    if (idx >= Nrows * ng) return;
    int n = idx / ng, f8 = idx - n * ng;
    int fbase = f8 * 8;
    const float* hrow = h + (size_t)n * F;

    ushort8 out[9];
    #pragma unroll
    for (int i = 0; i < 8; ++i) {
        int f = fbase + i;
        bool valid = f < F;
        float x = valid ? hrow[f] : 0.0f;
        float v[9];
        kan_phi(x, v);
        #pragma unroll
        for (int j = 0; j < 9; ++j)
            out[j][i] = valid ? f2bf(v[j]) : (unsigned short)0;
    }
    size_t rowoff = (size_t)n * (size_t)(9 * Fp);
    #pragma unroll
    for (int j = 0; j < 9; ++j)
        *reinterpret_cast<ushort8*>(phi + rowoff + (size_t)j * Fp + fbase) = out[j];
}

// ---- pack W^T (O x 9*Fp bf16), basis-major: Wt[o, j*Fp + f].
//      slot j=0 = base_w, slots 1..8 = spline_w[...,j-1] * scaler. ----
__global__ void pack_w_kernel(const float* __restrict__ bw,
                              const float* __restrict__ sw,
                              const float* __restrict__ sc,
                              unsigned short* __restrict__ wt,
                              int O, int F, int Fp) {
    int ng = Fp >> 3;
    int idx = blockIdx.x * blockDim.x + threadIdx.x;
    if (idx >= O * ng) return;
    int o = idx / ng, f8 = idx - o * ng;
    int fbase = f8 * 8;

    ushort8 outb;
    ushort8 outs[8];
    #pragma unroll
    for (int i = 0; i < 8; ++i) {
        int f = fbase + i;
        bool valid = f < F;
        size_t s = (size_t)o * F + f;
        float b     = valid ? bw[s] : 0.0f;
        float scale = valid ? sc[s] : 0.0f;
        outb[i] = valid ? f2bf(b) : (unsigned short)0;
        #pragma unroll
        for (int j = 0; j < 8; ++j) {
            float w = valid ? sw[s * 8 + j] : 0.0f;
            outs[j][i] = valid ? f2bf(w * scale) : (unsigned short)0;
        }
    }
    size_t rowoff = (size_t)o * (size_t)(9 * Fp);
    *reinterpret_cast<ushort8*>(wt + rowoff + fbase) = outb;
    #pragma unroll
    for (int j = 0; j < 8; ++j)
        *reinterpret_cast<ushort8*>(wt + rowoff + (size_t)(j + 1) * Fp + fbase) = outs[j];
}

// ---- bf16 GEMM: C(MxN fp32) = A(MxK bf16, row-major) * B^T(NxK bf16, row-major) ----
// m97 structure: 128 x (32*NT) tile, BK=64, global_load_lds width 16, XOR-swizzled LDS.
// NT=4 -> 128x128 tile; NT=2 -> 128x64 tile (for small-N layer 2: 2x the blocks).
template<int NT>
__global__ __launch_bounds__(256, 2)
void gemm_bt_kernel(const unsigned short* __restrict__ A,
                    const unsigned short* __restrict__ B,
                    float* __restrict__ C,
                    int M, int N, int K) {
    constexpr int BN = 32 * NT;
    __shared__ __align__(16) unsigned short Alds[128 * 64];
    __shared__ __align__(16) unsigned short Blds[BN * 64];

    const int tid  = threadIdx.x;
    const int wave = tid >> 6;
    const int lane = tid & 63;
    const int bm = blockIdx.y;
    const int bn = blockIdx.x;
    const int wm = (wave >> 1) * 64;
    const int wn = (wave & 1) * (16 * NT);

    floatx4 zero = {0.f, 0.f, 0.f, 0.f};
    floatx4 acc[4][NT];
    #pragma unroll
    for (int i = 0; i < 4; ++i)
        #pragma unroll
        for (int j = 0; j < NT; ++j)
            acc[i][j] = zero;

    // staging pattern: linear chunk q -> (row, physChunk); logical chunk = phys ^ (row&7)
    int srow[4], scol[4];
    #pragma unroll
    for (int r = 0; r < 4; ++r) {
        int q = (r * 4 + wave) * 64 + lane;
        int row = q >> 3;
        int p = q & 7;
        srow[r] = row;
        scol[r] = (p ^ (row & 7)) * 8;   // element offset within the 64-wide k-tile
    }

    const unsigned short* Ab = A + (size_t)bm * 128 * K;
    const unsigned short* Bb = B + (size_t)bn * BN * K;

    const int fr = lane & 15;   // m (or n) within 16x16 tile
    const int fq = lane >> 4;   // quad 0..3 -> k chunk

    for (int k0 = 0; k0 < K; k0 += 64) {
        #pragma unroll
        for (int r = 0; r < 4; ++r) {
            __builtin_amdgcn_global_load_lds(
                (const GLOBAL_AS void*)(Ab + (size_t)srow[r] * K + (k0 + scol[r])),
                (LDS_AS void*)(Alds + (r * 4 + wave) * 512),
                16, 0, 0);
        }
        #pragma unroll
        for (int r = 0; r < NT; ++r) {
            __builtin_amdgcn_global_load_lds(
                (const GLOBAL_AS void*)(Bb + (size_t)srow[r] * K + (k0 + scol[r])),
                (LDS_AS void*)(Blds + (r * 4 + wave) * 512),
                16, 0, 0);
        }
        __syncthreads();

        #pragma unroll
        for (int ks = 0; ks < 2; ++ks) {
            bf16x8 av[4], bv[NT];
            #pragma unroll
            for (int mt = 0; mt < 4; ++mt) {
                int row = wm + mt * 16 + fr;
                int c   = ks * 4 + fq;
                int off = row * 64 + ((c ^ (row & 7)) * 8);
                av[mt] = *reinterpret_cast<const bf16x8*>(&Alds[off]);
            }
            #pragma unroll
            for (int nt = 0; nt < NT; ++nt) {
                int row = wn + nt * 16 + fr;
                int c   = ks * 4 + fq;
                int off = row * 64 + ((c ^ (row & 7)) * 8);
                bv[nt] = *reinterpret_cast<const bf16x8*>(&Blds[off]);
            }
            #pragma unroll
            for (int mt = 0; mt < 4; ++mt)
                #pragma unroll
                for (int nt = 0; nt < NT; ++nt)
                    acc[mt][nt] = __builtin_amdgcn_mfma_f32_16x16x32_bf16(
                        av[mt], bv[nt], acc[mt][nt], 0, 0, 0);
        }
        __syncthreads();
    }

    // epilogue: C/D layout col = lane&15, row = (lane>>4)*4 + reg  [m89 verified]
    const int rq = fq * 4;
    #pragma unroll
    for (int mt = 0; mt < 4; ++mt) {
        #pragma unroll
        for (int nt = 0; nt < NT; ++nt) {
            #pragma unroll
            for (int r = 0; r < 4; ++r) {
                int gr = bm * 128 + wm + mt * 16 + rq + r;
                int gc = bn * BN + wn + nt * 16 + fr;
                C[(size_t)gr * N + gc] = acc[mt][nt][r];
            }
        }
    }
}

extern "C" void kernel_launch(void* const* d_in, const int* in_sizes, int n_in,
                              void* d_out, int out_size, void* d_ws, size_t ws_size,
                              hipStream_t stream) {
    const float* xs  = (const float*)d_in[0];
    const float* ys  = (const float*)d_in[1];
    const float* bw0 = (const float*)d_in[2];
    const float* sw0 = (const float*)d_in[3];
    const float* sc0 = (const float*)d_in[4];
    const float* bw1 = (const float*)d_in[5];
    const float* sw1 = (const float*)d_in[6];
    const float* sc1 = (const float*)d_in[7];
    const float* bw2 = (const float*)d_in[8];
    const float* sw2 = (const float*)d_in[9];
    const float* sc2 = (const float*)d_in[10];

    // workspace layout (bytes)
    char* ws = (char*)d_ws;
    unsigned short* Phi = (unsigned short*)ws;                         // 4096*18432*2 = 150,994,944
    unsigned short* Wt  = (unsigned short*)(ws + 150994944);           // 18432*2048*2 =  75,497,472
    float* h0 = (float*)(ws + 150994944 + 75497472);                   // 4096*1023*4  =  16,760,832
    float* h1 = (float*)((char*)h0 + 16760832);                        // 4096*2048*4  =  33,554,432
    float* h2 = (float*)((char*)h1 + 33554432);                        // 4096*2048*4  =  33,554,432
    (void)ws_size; (void)in_sizes; (void)n_in; (void)out_size;

    const int T = 256;

    // stage 0: input interleave
    build_h0_kernel<<<(M_BATCH * F0 + T - 1) / T, T, 0, stream>>>(xs, ys, h0);

    // ---- layer 0: 4096 x 9216 x 2048 ----
    pack_w_kernel<<<(EMB * (F0P / 8) + T - 1) / T, T, 0, stream>>>(bw0, sw0, sc0, Wt, EMB, F0, F0P);
    expand_kernel<<<(M_BATCH * (F0P / 8) + T - 1) / T, T, 0, stream>>>(h0, Phi, M_BATCH, F0, F0P);
    gemm_bt_kernel<4><<<dim3(EMB / 128, M_BATCH / 128), T, 0, stream>>>(Phi, Wt, h1, M_BATCH, EMB, K0);

    // ---- layer 1: 4096 x 18432 x 2048 ----
    pack_w_kernel<<<(EMB * (EMB / 8) + T - 1) / T, T, 0, stream>>>(bw1, sw1, sc1, Wt, EMB, EMB, EMB);
    expand_kernel<<<(M_BATCH * (EMB / 8) + T - 1) / T, T, 0, stream>>>(h1, Phi, M_BATCH, EMB, EMB);
    gemm_bt_kernel<4><<<dim3(EMB / 128, M_BATCH / 128), T, 0, stream>>>(Phi, Wt, h2, M_BATCH, EMB, K12);

    // ---- layer 2: 4096 x 18432 x 512, 128x64 tiles -> 256 blocks (full CU coverage) ----
    pack_w_kernel<<<(NPTS * (EMB / 8) + T - 1) / T, T, 0, stream>>>(bw2, sw2, sc2, Wt, NPTS, EMB, EMB);
    expand_kernel<<<(M_BATCH * (EMB / 8) + T - 1) / T, T, 0, stream>>>(h2, Phi, M_BATCH, EMB, EMB);
    gemm_bt_kernel<2><<<dim3(NPTS / 64, M_BATCH / 128), T, 0, stream>>>(Phi, Wt, (float*)d_out, M_BATCH, NPTS, K12);
}

// Round 3
// 1484.896 us; speedup vs baseline: 1.3290x; 1.3290x over previous
//
#include <hip/hip_runtime.h>

#define GLOBAL_AS __attribute__((address_space(1)))
#define LDS_AS    __attribute__((address_space(3)))

typedef __bf16 bf16x8 __attribute__((ext_vector_type(8)));
typedef float  floatx4 __attribute__((ext_vector_type(4)));
typedef unsigned short ushort8 __attribute__((ext_vector_type(8)));

static constexpr int M_BATCH = 4096;
static constexpr int NPTS    = 512;
static constexpr int EMB     = 2048;
static constexpr int F0      = 1023;     // 2*NPTS-1
static constexpr int F0P     = 1024;     // padded feature count, K multiple of 64
static constexpr int K0      = 9 * F0P;  // 9216
static constexpr int K12     = 9 * EMB;  // 18432

// ---- float -> bf16 round-to-nearest-even ----
__device__ __forceinline__ unsigned short f2bf(float f) {
    unsigned int u = __float_as_uint(f);
    u += 0x7fffu + ((u >> 16) & 1u);
    return (unsigned short)(u >> 16);
}

// ---- relu + 8 cubic B-spline bases, mirroring the reference recursion ----
__device__ __forceinline__ void kan_phi(float x, float* v) {
    float g[12];
    #pragma unroll
    for (int i = 0; i < 12; ++i) g[i] = (float)(i - 3) * 0.4f - 1.0f;
    float b[11];
    #pragma unroll
    for (int i = 0; i < 11; ++i) b[i] = (x >= g[i] && x < g[i + 1]) ? 1.0f : 0.0f;
    #pragma unroll
    for (int k = 1; k <= 3; ++k) {
        #pragma unroll
        for (int i = 0; i + k < 11; ++i) {
            float left  = (x - g[i]) / (g[i + k] - g[i]);
            float right = (g[i + k + 1] - x) / (g[i + k + 1] - g[i + 1]);
            b[i] = left * b[i] + right * b[i + 1];
        }
    }
    v[0] = x > 0.0f ? x : 0.0f;
    #pragma unroll
    for (int i = 0; i < 8; ++i) v[1 + i] = b[i];
}

// ---- build h0 (4096 x 1023): interleave xs[:, :-1], ys[:, :-1], then xs[:, -1] ----
__global__ void build_h0_kernel(const float* __restrict__ xs,
                                const float* __restrict__ ys,
                                float* __restrict__ h0) {
    int idx = blockIdx.x * blockDim.x + threadIdx.x;
    if (idx >= M_BATCH * F0) return;
    int n = idx / F0, c = idx - n * F0;
    float v;
    if (c == F0 - 1) v = xs[n * NPTS + NPTS - 1];
    else {
        int i = c >> 1;
        v = (c & 1) ? ys[n * NPTS + i] : xs[n * NPTS + i];
    }
    h0[idx] = v;
}

// ---- expand: one block per row n. Lane<->feature (coalesced 4B reads),
//      LDS image laid out exactly as the global row [j*Fp + f], flat
//      ushort8 copy-out (16B/lane both sides). ----
template<int FP>
__global__ __launch_bounds__(256)
void expand_kernel(const float* __restrict__ h,
                   unsigned short* __restrict__ phi,
                   int F) {
    __shared__ __align__(16) unsigned short ebuf[9 * FP];
    const int n = blockIdx.x;
    const int tid = threadIdx.x;
    const float* hrow = h + (size_t)n * F;

    for (int f = tid; f < FP; f += 256) {
        bool valid = f < F;
        float x = valid ? hrow[f] : 0.0f;
        float v[9];
        kan_phi(x, v);
        #pragma unroll
        for (int j = 0; j < 9; ++j)
            ebuf[j * FP + f] = valid ? f2bf(v[j]) : (unsigned short)0;
    }
    __syncthreads();

    unsigned short* dst = phi + (size_t)n * (size_t)(9 * FP);
    for (int t = tid; t < (9 * FP) / 8; t += 256)
        *reinterpret_cast<ushort8*>(dst + t * 8) =
            *reinterpret_cast<const ushort8*>(ebuf + t * 8);
}

// ---- pack W^T: one block per output row o. Coalesced float4 reads of sw
//      (lane-consecutive flat index), LDS transpose with +8 pad (kills the
//      8-way bank alias), per-j ushort8 copy-out. ----
template<int FP>
__global__ __launch_bounds__(256)
void pack_w_kernel(const float* __restrict__ bw,
                   const float* __restrict__ sw,
                   const float* __restrict__ sc,
                   unsigned short* __restrict__ wt,
                   int F) {
    constexpr int FPP = FP + 8;            // padded LDS stride (FPP % 8 == 0)
    __shared__ __align__(16) unsigned short wbuf[9 * FPP];
    __shared__ float scb[FP];
    const int o = blockIdx.x;
    const int tid = threadIdx.x;

    // phase 1: stage scaler, fill slot 0 (base_w), zero padding columns
    for (int f = tid; f < FP; f += 256) {
        bool valid = f < F;
        size_t s = (size_t)o * F + f;
        scb[f] = valid ? sc[s] : 0.0f;
        wbuf[0 * FPP + f] = valid ? f2bf(bw[s]) : (unsigned short)0;
        if (!valid) {
            #pragma unroll
            for (int j = 1; j < 9; ++j) wbuf[j * FPP + f] = 0;
        }
    }
    __syncthreads();

    // phase 2: flat coalesced float4 reads of the sw row, scatter into LDS
    const float4* sw4 = reinterpret_cast<const float4*>(sw + (size_t)o * F * 8);
    const int n4 = 2 * F;                  // number of float4s in the row
    for (int t = tid; t < n4; t += 256) {
        float4 v = sw4[t];
        int flat = t * 4;
        #pragma unroll
        for (int c = 0; c < 4; ++c) {
            int fl = flat + c;
            int f = fl >> 3;
            int j = (fl & 7) + 1;
            float x = (c == 0) ? v.x : (c == 1) ? v.y : (c == 2) ? v.z : v.w;
            wbuf[j * FPP + f] = f2bf(x * scb[f]);
        }
    }
    __syncthreads();

    // phase 3: per-j contiguous copy-out (16B/lane both sides)
    unsigned short* dst = wt + (size_t)o * (size_t)(9 * FP);
    #pragma unroll
    for (int j = 0; j < 9; ++j)
        for (int t = tid; t < FP / 8; t += 256)
            *reinterpret_cast<ushort8*>(dst + (size_t)j * FP + t * 8) =
                *reinterpret_cast<const ushort8*>(wbuf + j * FPP + t * 8);
}

// ---- bf16 GEMM: C(MxN fp32) = A(MxK) * B^T(NxK), 128x128 tile, BK=64,
//      global_load_lds width 16, XOR-swizzled LDS, XCD-aware block swizzle,
//      optional split-K via blockIdx.z (kchunk = K / gridDim.z). ----
__global__ __launch_bounds__(256, 2)
void gemm_bt_kernel(const unsigned short* __restrict__ A,
                    const unsigned short* __restrict__ B,
                    float* __restrict__ C,
                    int M, int N, int K, int kchunk) {
    __shared__ __align__(16) unsigned short Alds[128 * 64];
    __shared__ __align__(16) unsigned short Blds[128 * 64];

    const int tid  = threadIdx.x;
    const int wave = tid >> 6;
    const int lane = tid & 63;

    // XCD-aware swizzle: assume XCD = linear_id % 8. Group same-XCD blocks
    // onto shared A-strips (grid.x==16) or shared B-strips (grid.x==4).
    int id = blockIdx.y * gridDim.x + blockIdx.x;
    int bm, bn;
    if (gridDim.x == 16) {
        int g = id & 7, s = id >> 3;
        bn = g + 8 * (s & 1);
        bm = s >> 1;
    } else if (gridDim.x == 4) {
        int g = id & 7, s = id >> 3;
        bn = g & 3;
        bm = 2 * s + (g >> 2);
    } else {
        bn = blockIdx.x; bm = blockIdx.y;
    }

    const int wm = (wave >> 1) * 64;
    const int wn = (wave & 1) * 64;
    const int kbase = blockIdx.z * kchunk;
    float* Cz = C + (size_t)blockIdx.z * (size_t)M * N;

    floatx4 zero = {0.f, 0.f, 0.f, 0.f};
    floatx4 acc[4][4];
    #pragma unroll
    for (int i = 0; i < 4; ++i)
        #pragma unroll
        for (int j = 0; j < 4; ++j)
            acc[i][j] = zero;

    int srow[4], scol[4];
    #pragma unroll
    for (int r = 0; r < 4; ++r) {
        int q = (r * 4 + wave) * 64 + lane;
        int row = q >> 3;
        int p = q & 7;
        srow[r] = row;
        scol[r] = (p ^ (row & 7)) * 8;
    }

    const unsigned short* Ab = A + (size_t)bm * 128 * K;
    const unsigned short* Bb = B + (size_t)bn * 128 * K;

    const int fr = lane & 15;
    const int fq = lane >> 4;

    for (int k0 = kbase; k0 < kbase + kchunk; k0 += 64) {
        #pragma unroll
        for (int r = 0; r < 4; ++r) {
            __builtin_amdgcn_global_load_lds(
                (const GLOBAL_AS void*)(Ab + (size_t)srow[r] * K + (k0 + scol[r])),
                (LDS_AS void*)(Alds + (r * 4 + wave) * 512),
                16, 0, 0);
        }
        #pragma unroll
        for (int r = 0; r < 4; ++r) {
            __builtin_amdgcn_global_load_lds(
                (const GLOBAL_AS void*)(Bb + (size_t)srow[r] * K + (k0 + scol[r])),
                (LDS_AS void*)(Blds + (r * 4 + wave) * 512),
                16, 0, 0);
        }
        __syncthreads();

        #pragma unroll
        for (int ks = 0; ks < 2; ++ks) {
            bf16x8 av[4], bv[4];
            #pragma unroll
            for (int mt = 0; mt < 4; ++mt) {
                int row = wm + mt * 16 + fr;
                int c   = ks * 4 + fq;
                int off = row * 64 + ((c ^ (row & 7)) * 8);
                av[mt] = *reinterpret_cast<const bf16x8*>(&Alds[off]);
            }
            #pragma unroll
            for (int nt = 0; nt < 4; ++nt) {
                int row = wn + nt * 16 + fr;
                int c   = ks * 4 + fq;
                int off = row * 64 + ((c ^ (row & 7)) * 8);
                bv[nt] = *reinterpret_cast<const bf16x8*>(&Blds[off]);
            }
            #pragma unroll
            for (int mt = 0; mt < 4; ++mt)
                #pragma unroll
                for (int nt = 0; nt < 4; ++nt)
                    acc[mt][nt] = __builtin_amdgcn_mfma_f32_16x16x32_bf16(
                        av[mt], bv[nt], acc[mt][nt], 0, 0, 0);
        }
        __syncthreads();
    }

    // epilogue: C/D layout col = lane&15, row = (lane>>4)*4 + reg
    const int rq = fq * 4;
    #pragma unroll
    for (int mt = 0; mt < 4; ++mt) {
        #pragma unroll
        for (int nt = 0; nt < 4; ++nt) {
            #pragma unroll
            for (int r = 0; r < 4; ++r) {
                int gr = bm * 128 + wm + mt * 16 + rq + r;
                int gc = bn * 128 + wn + nt * 16 + fr;
                Cz[(size_t)gr * N + gc] = acc[mt][nt][r];
            }
        }
    }
}

// ---- split-K fixup: out = a + b ----
__global__ void add2_kernel(const float* __restrict__ a,
                            const float* __restrict__ b,
                            float* __restrict__ out, int n4) {
    int i = blockIdx.x * blockDim.x + threadIdx.x;
    if (i >= n4) return;
    float4 x = reinterpret_cast<const float4*>(a)[i];
    float4 y = reinterpret_cast<const float4*>(b)[i];
    float4 z = {x.x + y.x, x.y + y.y, x.z + y.z, x.w + y.w};
    reinterpret_cast<float4*>(out)[i] = z;
}

extern "C" void kernel_launch(void* const* d_in, const int* in_sizes, int n_in,
                              void* d_out, int out_size, void* d_ws, size_t ws_size,
                              hipStream_t stream) {
    const float* xs  = (const float*)d_in[0];
    const float* ys  = (const float*)d_in[1];
    const float* bw0 = (const float*)d_in[2];
    const float* sw0 = (const float*)d_in[3];
    const float* sc0 = (const float*)d_in[4];
    const float* bw1 = (const float*)d_in[5];
    const float* sw1 = (const float*)d_in[6];
    const float* sc1 = (const float*)d_in[7];
    const float* bw2 = (const float*)d_in[8];
    const float* sw2 = (const float*)d_in[9];
    const float* sc2 = (const float*)d_in[10];

    // workspace layout (bytes)
    char* ws = (char*)d_ws;
    unsigned short* Phi = (unsigned short*)ws;                         // 150,994,944
    unsigned short* Wt  = (unsigned short*)(ws + 150994944);           //  75,497,472
    float* h0 = (float*)(ws + 150994944 + 75497472);                   //  16,760,832
    float* h1 = (float*)((char*)h0 + 16760832);                        //  33,554,432
    float* h2 = (float*)((char*)h1 + 33554432);                        //  33,554,432
    float* Cpart = h1;  // layer-2 split-K partials (16.8 MB) alias dead h1
    (void)ws_size; (void)in_sizes; (void)n_in; (void)out_size;

    const int T = 256;

    build_h0_kernel<<<(M_BATCH * F0 + T - 1) / T, T, 0, stream>>>(xs, ys, h0);

    // ---- layer 0: 4096 x 9216 x 2048 ----
    pack_w_kernel<F0P><<<EMB, T, 0, stream>>>(bw0, sw0, sc0, Wt, F0);
    expand_kernel<F0P><<<M_BATCH, T, 0, stream>>>(h0, Phi, F0);
    gemm_bt_kernel<<<dim3(16, 32, 1), T, 0, stream>>>(Phi, Wt, h1, M_BATCH, EMB, K0, K0);

    // ---- layer 1: 4096 x 18432 x 2048 ----
    pack_w_kernel<EMB><<<EMB, T, 0, stream>>>(bw1, sw1, sc1, Wt, EMB);
    expand_kernel<EMB><<<M_BATCH, T, 0, stream>>>(h1, Phi, EMB);
    gemm_bt_kernel<<<dim3(16, 32, 1), T, 0, stream>>>(Phi, Wt, h2, M_BATCH, EMB, K12, K12);

    // ---- layer 2: 4096 x 18432 x 512, split-K=2 -> 256 blocks ----
    pack_w_kernel<EMB><<<NPTS, T, 0, stream>>>(bw2, sw2, sc2, Wt, EMB);
    expand_kernel<EMB><<<M_BATCH, T, 0, stream>>>(h2, Phi, EMB);
    gemm_bt_kernel<<<dim3(4, 32, 2), T, 0, stream>>>(Phi, Wt, Cpart, M_BATCH, NPTS, K12, K12 / 2);
    add2_kernel<<<(M_BATCH * NPTS / 4 + T - 1) / T, T, 0, stream>>>(
        Cpart, Cpart + (size_t)M_BATCH * NPTS, (float*)d_out, M_BATCH * NPTS / 4);
}

// Round 4
// 1357.408 us; speedup vs baseline: 1.4538x; 1.0939x over previous
//
#include <hip/hip_runtime.h>

#define GLOBAL_AS __attribute__((address_space(1)))
#define LDS_AS    __attribute__((address_space(3)))

typedef __bf16 bf16x8 __attribute__((ext_vector_type(8)));
typedef float  floatx4 __attribute__((ext_vector_type(4)));
typedef unsigned short ushort8 __attribute__((ext_vector_type(8)));

static constexpr int M_BATCH = 4096;
static constexpr int NPTS    = 512;
static constexpr int EMB     = 2048;
static constexpr int F0      = 1023;     // 2*NPTS-1
static constexpr int F0P     = 1024;     // padded feature count, K multiple of 64
static constexpr int K0      = 9 * F0P;  // 9216
static constexpr int K12     = 9 * EMB;  // 18432

// ---- float -> bf16 round-to-nearest-even ----
__device__ __forceinline__ unsigned short f2bf(float f) {
    unsigned int u = __float_as_uint(f);
    u += 0x7fffu + ((u >> 16) & 1u);
    return (unsigned short)(u >> 16);
}

// ---- relu + 8 cubic B-spline bases, mirroring the reference recursion ----
__device__ __forceinline__ void kan_phi(float x, float* v) {
    float g[12];
    #pragma unroll
    for (int i = 0; i < 12; ++i) g[i] = (float)(i - 3) * 0.4f - 1.0f;
    float b[11];
    #pragma unroll
    for (int i = 0; i < 11; ++i) b[i] = (x >= g[i] && x < g[i + 1]) ? 1.0f : 0.0f;
    #pragma unroll
    for (int k = 1; k <= 3; ++k) {
        #pragma unroll
        for (int i = 0; i + k < 11; ++i) {
            float left  = (x - g[i]) / (g[i + k] - g[i]);
            float right = (g[i + k + 1] - x) / (g[i + k + 1] - g[i + 1]);
            b[i] = left * b[i] + right * b[i + 1];
        }
    }
    v[0] = x > 0.0f ? x : 0.0f;
    #pragma unroll
    for (int i = 0; i < 8; ++i) v[1 + i] = b[i];
}

// ---- zero-init h1 / h2 / d_out (atomic split-K epilogue needs zeros) ----
__global__ void zero3_kernel(float4* a, int na, float4* b, int nb,
                             float4* c, int nc) {
    float4 z = {0.f, 0.f, 0.f, 0.f};
    int stride = gridDim.x * blockDim.x;
    int i = blockIdx.x * blockDim.x + threadIdx.x;
    for (int t = i; t < na; t += stride) a[t] = z;
    for (int t = i; t < nb; t += stride) b[t] = z;
    for (int t = i; t < nc; t += stride) c[t] = z;
}

// ---- expand: one block per row n. MODE 0: read h[n*F+f]. MODE 1: gather
//      the interleaved KAN input directly from xs/ys (kills build_h0).
//      LDS image laid out exactly as the global row [j*FP + f], flat
//      ushort8 copy-out (16B/lane both sides). ----
template<int FP, int MODE>
__global__ __launch_bounds__(256)
void expand_kernel(const float* __restrict__ h,
                   const float* __restrict__ ys,
                   unsigned short* __restrict__ phi,
                   int F) {
    __shared__ __align__(16) unsigned short ebuf[9 * FP];
    const int n = blockIdx.x;
    const int tid = threadIdx.x;

    for (int f = tid; f < FP; f += 256) {
        bool valid = f < F;
        float x;
        if (MODE == 1) {
            // f even: xs[n, f>>1]; f odd: ys[n, f>>1]; f==1022 -> xs[n,511]
            const float* src = (f & 1) ? ys : h;
            x = valid ? src[(size_t)n * NPTS + (f >> 1)] : 0.0f;
        } else {
            x = valid ? h[(size_t)n * F + f] : 0.0f;
        }
        float v[9];
        kan_phi(x, v);
        #pragma unroll
        for (int j = 0; j < 9; ++j)
            ebuf[j * FP + f] = valid ? f2bf(v[j]) : (unsigned short)0;
    }
    __syncthreads();

    unsigned short* dst = phi + (size_t)n * (size_t)(9 * FP);
    for (int t = tid; t < (9 * FP) / 8; t += 256)
        *reinterpret_cast<ushort8*>(dst + t * 8) =
            *reinterpret_cast<const ushort8*>(ebuf + t * 8);
}

// ---- pack W^T: one block per output row o. Coalesced float4 reads of sw,
//      LDS transpose with +8 pad, per-j ushort8 copy-out. ----
template<int FP>
__global__ __launch_bounds__(256)
void pack_w_kernel(const float* __restrict__ bw,
                   const float* __restrict__ sw,
                   const float* __restrict__ sc,
                   unsigned short* __restrict__ wt,
                   int F) {
    constexpr int FPP = FP + 8;
    __shared__ __align__(16) unsigned short wbuf[9 * FPP];
    __shared__ float scb[FP];
    const int o = blockIdx.x;
    const int tid = threadIdx.x;

    for (int f = tid; f < FP; f += 256) {
        bool valid = f < F;
        size_t s = (size_t)o * F + f;
        scb[f] = valid ? sc[s] : 0.0f;
        wbuf[0 * FPP + f] = valid ? f2bf(bw[s]) : (unsigned short)0;
        if (!valid) {
            #pragma unroll
            for (int j = 1; j < 9; ++j) wbuf[j * FPP + f] = 0;
        }
    }
    __syncthreads();

    const float4* sw4 = reinterpret_cast<const float4*>(sw + (size_t)o * F * 8);
    const int n4 = 2 * F;
    for (int t = tid; t < n4; t += 256) {
        float4 v = sw4[t];
        int flat = t * 4;
        #pragma unroll
        for (int c = 0; c < 4; ++c) {
            int fl = flat + c;
            int f = fl >> 3;
            int j = (fl & 7) + 1;
            float x = (c == 0) ? v.x : (c == 1) ? v.y : (c == 2) ? v.z : v.w;
            wbuf[j * FPP + f] = f2bf(x * scb[f]);
        }
    }
    __syncthreads();

    unsigned short* dst = wt + (size_t)o * (size_t)(9 * FP);
    #pragma unroll
    for (int j = 0; j < 9; ++j)
        for (int t = tid; t < FP / 8; t += 256)
            *reinterpret_cast<ushort8*>(dst + (size_t)j * FP + t * 8) =
                *reinterpret_cast<const ushort8*>(wbuf + j * FPP + t * 8);
}

// ---- bf16 GEMM: C(MxN fp32) += A(MxK) * B^T(NxK), 128x128 tile, BK=64,
//      global_load_lds width 16, XOR-swizzled LDS. Split-K via blockIdx.z
//      (kchunk = K / gridDim.z), fp32 atomicAdd epilogue (C pre-zeroed;
//      device-scope atomics are XCD-safe). ----
__global__ __launch_bounds__(256, 2)
void gemm_bt_kernel(const unsigned short* __restrict__ A,
                    const unsigned short* __restrict__ B,
                    float* __restrict__ C,
                    int M, int N, int K, int kchunk) {
    __shared__ __align__(16) unsigned short Alds[128 * 64];
    __shared__ __align__(16) unsigned short Blds[128 * 64];

    const int tid  = threadIdx.x;
    const int wave = tid >> 6;
    const int lane = tid & 63;
    const int bm = blockIdx.y;
    const int bn = blockIdx.x;
    const int wm = (wave >> 1) * 64;
    const int wn = (wave & 1) * 64;
    const int kbase = blockIdx.z * kchunk;

    floatx4 zero = {0.f, 0.f, 0.f, 0.f};
    floatx4 acc[4][4];
    #pragma unroll
    for (int i = 0; i < 4; ++i)
        #pragma unroll
        for (int j = 0; j < 4; ++j)
            acc[i][j] = zero;

    int srow[4], scol[4];
    #pragma unroll
    for (int r = 0; r < 4; ++r) {
        int q = (r * 4 + wave) * 64 + lane;
        int row = q >> 3;
        int p = q & 7;
        srow[r] = row;
        scol[r] = (p ^ (row & 7)) * 8;
    }

    const unsigned short* Ab = A + (size_t)bm * 128 * K;
    const unsigned short* Bb = B + (size_t)bn * 128 * K;

    const int fr = lane & 15;
    const int fq = lane >> 4;

    for (int k0 = kbase; k0 < kbase + kchunk; k0 += 64) {
        #pragma unroll
        for (int r = 0; r < 4; ++r) {
            __builtin_amdgcn_global_load_lds(
                (const GLOBAL_AS void*)(Ab + (size_t)srow[r] * K + (k0 + scol[r])),
                (LDS_AS void*)(Alds + (r * 4 + wave) * 512),
                16, 0, 0);
        }
        #pragma unroll
        for (int r = 0; r < 4; ++r) {
            __builtin_amdgcn_global_load_lds(
                (const GLOBAL_AS void*)(Bb + (size_t)srow[r] * K + (k0 + scol[r])),
                (LDS_AS void*)(Blds + (r * 4 + wave) * 512),
                16, 0, 0);
        }
        __syncthreads();

        #pragma unroll
        for (int ks = 0; ks < 2; ++ks) {
            bf16x8 av[4], bv[4];
            #pragma unroll
            for (int mt = 0; mt < 4; ++mt) {
                int row = wm + mt * 16 + fr;
                int c   = ks * 4 + fq;
                int off = row * 64 + ((c ^ (row & 7)) * 8);
                av[mt] = *reinterpret_cast<const bf16x8*>(&Alds[off]);
            }
            #pragma unroll
            for (int nt = 0; nt < 4; ++nt) {
                int row = wn + nt * 16 + fr;
                int c   = ks * 4 + fq;
                int off = row * 64 + ((c ^ (row & 7)) * 8);
                bv[nt] = *reinterpret_cast<const bf16x8*>(&Blds[off]);
            }
            #pragma unroll
            for (int mt = 0; mt < 4; ++mt)
                #pragma unroll
                for (int nt = 0; nt < 4; ++nt)
                    acc[mt][nt] = __builtin_amdgcn_mfma_f32_16x16x32_bf16(
                        av[mt], bv[nt], acc[mt][nt], 0, 0, 0);
        }
        __syncthreads();
    }

    // epilogue: C/D layout col = lane&15, row = (lane>>4)*4 + reg
    const int rq = fq * 4;
    #pragma unroll
    for (int mt = 0; mt < 4; ++mt) {
        #pragma unroll
        for (int nt = 0; nt < 4; ++nt) {
            #pragma unroll
            for (int r = 0; r < 4; ++r) {
                int gr = bm * 128 + wm + mt * 16 + rq + r;
                int gc = bn * 128 + wn + nt * 16 + fr;
                atomicAdd(&C[(size_t)gr * N + gc], acc[mt][nt][r]);
            }
        }
    }
}

extern "C" void kernel_launch(void* const* d_in, const int* in_sizes, int n_in,
                              void* d_out, int out_size, void* d_ws, size_t ws_size,
                              hipStream_t stream) {
    const float* xs  = (const float*)d_in[0];
    const float* ys  = (const float*)d_in[1];
    const float* bw0 = (const float*)d_in[2];
    const float* sw0 = (const float*)d_in[3];
    const float* sc0 = (const float*)d_in[4];
    const float* bw1 = (const float*)d_in[5];
    const float* sw1 = (const float*)d_in[6];
    const float* sc1 = (const float*)d_in[7];
    const float* bw2 = (const float*)d_in[8];
    const float* sw2 = (const float*)d_in[9];
    const float* sc2 = (const float*)d_in[10];

    // workspace layout (bytes): Phi 151.0M | Wt 75.5M | h1 33.6M | h2 33.6M
    char* ws = (char*)d_ws;
    unsigned short* Phi = (unsigned short*)ws;
    unsigned short* Wt  = (unsigned short*)(ws + 150994944);
    float* h1 = (float*)(ws + 150994944 + 75497472);
    float* h2 = (float*)((char*)h1 + 33554432);
    float* out = (float*)d_out;
    (void)ws_size; (void)in_sizes; (void)n_in; (void)out_size;

    const int T = 256;

    // zero accumulators for the atomic split-K epilogues
    zero3_kernel<<<2048, T, 0, stream>>>(
        (float4*)h1, M_BATCH * EMB / 4,
        (float4*)h2, M_BATCH * EMB / 4,
        (float4*)out, M_BATCH * NPTS / 4);

    // ---- layer 0: 4096 x 9216 x 2048, split-K=2 (1024 blocks) ----
    expand_kernel<F0P, 1><<<M_BATCH, T, 0, stream>>>(xs, ys, Phi, F0);
    pack_w_kernel<F0P><<<EMB, T, 0, stream>>>(bw0, sw0, sc0, Wt, F0);
    gemm_bt_kernel<<<dim3(16, 32, 2), T, 0, stream>>>(Phi, Wt, h1, M_BATCH, EMB, K0, K0 / 2);

    // ---- layer 1: 4096 x 18432 x 2048, split-K=2 (1024 blocks) ----
    expand_kernel<EMB, 0><<<M_BATCH, T, 0, stream>>>(h1, nullptr, Phi, EMB);
    pack_w_kernel<EMB><<<EMB, T, 0, stream>>>(bw1, sw1, sc1, Wt, EMB);
    gemm_bt_kernel<<<dim3(16, 32, 2), T, 0, stream>>>(Phi, Wt, h2, M_BATCH, EMB, K12, K12 / 2);

    // ---- layer 2: 4096 x 18432 x 512, split-K=4 (512 blocks) ----
    expand_kernel<EMB, 0><<<M_BATCH, T, 0, stream>>>(h2, nullptr, Phi, EMB);
    pack_w_kernel<EMB><<<NPTS, T, 0, stream>>>(bw2, sw2, sc2, Wt, EMB);
    gemm_bt_kernel<<<dim3(4, 32, 4), T, 0, stream>>>(Phi, Wt, out, M_BATCH, NPTS, K12, K12 / 4);
}